// Round 7
// baseline (140.445 us; speedup 1.0000x reference)
//
#include <hip/hip_runtime.h>
#include <hip/hip_bf16.h>
#include <stdint.h>

#define NIMG 8
#define CIN  64
#define HWI  12544      // 112*112
#define NP   100352     // 8*12544
#define COUT 128

typedef short v8s __attribute__((ext_vector_type(8)));   // 8 bf16 (4 VGPRs)
typedef float v4f __attribute__((ext_vector_type(4)));   // 4 fp32 acc

// fake-quant to int grid: round(x*inv) clamped to [lo,hi]
static __device__ __forceinline__ int q8(float x, float inv, float lo, float hi) {
    float t = rintf(x * inv);
    t = fminf(fmaxf(t, lo), hi);
    return (int)t;
}

// funnel shift: bytes of ({hi,lo} >> sh) — compiler emits v_alignbit_b32
static __device__ __forceinline__ uint32_t funnel(uint32_t hi, uint32_t lo, int sh) {
    return (uint32_t)(((((uint64_t)hi) << 32) | (uint64_t)lo) >> sh);
}

// manual signed-byte dot4
static __device__ __forceinline__ int dot4(uint32_t a, uint32_t b, int c) {
    int acc = c;
    #pragma unroll
    for (int i = 0; i < 4; ++i)
        acc += (int)(int8_t)(a >> (8*i)) * (int)(int8_t)(b >> (8*i));
    return acc;
}

// exact int -> bf16 bits (|v| <= 256 fits in 8 significand bits)
static __device__ __forceinline__ short i2bf(int v) {
    union { float f; uint32_t u; } c; c.f = (float)v;
    return (short)(c.u >> 16);
}

// ---------------------------------------------------------------------------
// K0: quantize 1x1 weights into bf16 matrix [128 co][128 k]
//     k<64: w2q ; k>=64: wscq.  (values are exact small ints in bf16)
// ---------------------------------------------------------------------------
__global__ void __launch_bounds__(256) wprep_kernel(
    const float* __restrict__ w2, const float* __restrict__ wsc,
    const float* __restrict__ sw2p, const float* __restrict__ swscp,
    uint16_t* __restrict__ wbuf)
{
    int tid = threadIdx.x;
    int co = tid >> 1, h = tid & 1;          // h=0 -> w2 half, h=1 -> w_sc half
    const float* src = h ? wsc : w2;
    float inv = 1.0f / (h ? swscp[0] : sw2p[0]);
    uint16_t* dst = wbuf + co*128 + h*64;
    for (int k = 0; k < 64; ++k)
        dst[k] = (uint16_t)i2bf(q8(src[co*64 + k], inv, -128.0f, 127.0f));
}

// ---------------------------------------------------------------------------
// K1: quantize x -> xq int8 (LDS), depthwise 3x3 int, relu-quant,
//     write act[p][c]: bytes 0..63 = yq (uint8), 64..127 = xq (int8)
//     Block = (n, 2 output rows). 4 waves: (row, half-row) each.
//     LDS tile: [c][4 rows][116 cols], c-stride 468B (117 dwords, odd -> <=2-way)
// ---------------------------------------------------------------------------
__global__ void __launch_bounds__(256) dwq_kernel(
    const float* __restrict__ x, const float* __restrict__ w1,
    const float* __restrict__ sinp, const float* __restrict__ srelup,
    const float* __restrict__ sw1p,
    int8_t* __restrict__ act)
{
    __shared__ int8_t tile[64 * 468];
    int bid = blockIdx.x;
    int n = bid / 56, ht = bid - n*56, hb = ht*2;
    int tid = threadIdx.x;
    float sin_f = sinp[0];
    float inv_sin = 1.0f / sin_f;

    for (int i = 0; i < 28; ++i) {
        int id = tid + i*256;
        int c = id / 112; int rem = id - c*112;
        int r = rem / 28; int seg = rem - r*28;
        int grow = hb + r - 1;
        float4 v = make_float4(0.f, 0.f, 0.f, 0.f);
        if ((unsigned)grow < 112u)
            v = *(const float4*)(x + ((size_t)(n*64 + c) * HWI + grow*112 + seg*4));
        float vv[4] = {v.x, v.y, v.z, v.w};
        uint32_t pk = 0;
        #pragma unroll
        for (int e = 0; e < 4; ++e) {
            int q = q8(vv[e], inv_sin, -128.0f, 127.0f);
            pk |= (uint32_t)(q & 255) << (8*e);
        }
        *(uint32_t*)&tile[c*468 + r*116 + seg*4] = pk;
    }
    {
        int c = tid >> 2, r = tid & 3;
        *(uint32_t*)&tile[c*468 + r*116 + 112] = 0;
    }
    __syncthreads();

    int wave = tid >> 6, lane = tid & 63;
    int rsel = wave >> 1;
    int row  = hb + rsel;
    int half = wave & 1;
    int c = lane;

    float isw1 = 1.0f / sw1p[0];
    uint32_t wp[3];
    #pragma unroll
    for (int ky = 0; ky < 3; ++ky) {
        uint32_t pk = 0;
        #pragma unroll
        for (int kx = 0; kx < 3; ++kx) {
            int q = q8(w1[c*9 + ky*3 + kx], isw1, -128.0f, 127.0f);
            pk |= (uint32_t)(q & 255) << (8*kx);
        }
        wp[ky] = pk;
    }
    float r1 = (sin_f * sw1p[0]) / srelup[0];

    int base[3];
    #pragma unroll
    for (int r2 = 0; r2 < 3; ++r2) base[r2] = c*468 + (rsel + r2)*116;
    int w0b = 56*half;

    uint32_t Ar[3], Br[3], Cr[3];
    #pragma unroll
    for (int r2 = 0; r2 < 3; ++r2) {
        Ar[r2] = half ? *(uint32_t*)&tile[base[r2] + w0b - 4] : 0u;
        Br[r2] = *(uint32_t*)&tile[base[r2] + w0b];
        Cr[r2] = *(uint32_t*)&tile[base[r2] + w0b + 4];
    }
    size_t pbase = (size_t)n*HWI + (size_t)row*112 + w0b;

    for (int q = 0; q < 14; ++q) {
        int acc0 = 0, acc1 = 0, acc2 = 0, acc3 = 0;
        #pragma unroll
        for (int r2 = 0; r2 < 3; ++r2) {
            uint32_t d0 = funnel(Br[r2], Ar[r2], 24);
            uint32_t d1 = Br[r2];
            uint32_t d2 = funnel(Cr[r2], Br[r2], 8);
            uint32_t d3 = funnel(Cr[r2], Br[r2], 16);
            acc0 = dot4(d0, wp[r2], acc0);
            acc1 = dot4(d1, wp[r2], acc1);
            acc2 = dot4(d2, wp[r2], acc2);
            acc3 = dot4(d3, wp[r2], acc3);
        }
        int accs[4] = {acc0, acc1, acc2, acc3};
        uint32_t xdw = Br[1];
        int8_t* ap = act + (pbase + (size_t)q*4)*128 + c;
        #pragma unroll
        for (int j = 0; j < 4; ++j) {
            float t = rintf((float)accs[j] * r1);
            t = fminf(fmaxf(t, 0.0f), 255.0f);
            ap[(size_t)j*128]      = (int8_t)(int)t;                 // yq (uint8 bits)
            ap[(size_t)j*128 + 64] = (int8_t)((xdw >> (8*j)) & 255); // xq
        }
        #pragma unroll
        for (int r2 = 0; r2 < 3; ++r2) { Ar[r2] = Br[r2]; Br[r2] = Cr[r2]; }
        if (q < 13) {
            #pragma unroll
            for (int r2 = 0; r2 < 3; ++r2)
                Cr[r2] = *(uint32_t*)&tile[base[r2] + w0b + q*4 + 8];
        }
    }
}

// ---------------------------------------------------------------------------
// K2: GEMM via mfma_f32_16x16x32_bf16 (exact small ints in bf16).
//     M=128 (co), K=64(yq)+64(xq) in 4 segs of 32, N=128 px/block.
//     Epilogue: v = S2*acc2 + Ssc*accsc ; fake_quant(s_add) ; **FP32 store**.
// ---------------------------------------------------------------------------
__global__ void __launch_bounds__(256) gemm_kernel(
    const int8_t* __restrict__ act, const uint16_t* __restrict__ wbuf,
    const float* __restrict__ sinp, const float* __restrict__ srelup,
    const float* __restrict__ saddp, const float* __restrict__ sw2p,
    const float* __restrict__ swscp,
    float* __restrict__ out)
{
    int bid = blockIdx.x;                     // 784 blocks of 128 pixels
    int tid = threadIdx.x;
    int wave = tid >> 6, lane = tid & 63;
    int lr = lane >> 4, ln = lane & 15;
    int p0 = bid * 128;
    int nimg = bid / 98;                      // 12544/128 = 98 -> no n straddle
    int hw0 = (bid - nimg*98) * 128;

    float S2  = sw2p[0] * srelup[0];
    float Ssc = swscp[0] * sinp[0];
    float sadd = saddp[0];
    float inv_sadd = 1.0f / sadd;

    // A fragments: a[mi][seg], m = (wave*2+mi)*16 + ln, k = seg*32 + lr*8 + j
    v8s a[2][4];
    #pragma unroll
    for (int mi = 0; mi < 2; ++mi) {
        int m = (wave*2 + mi)*16 + ln;
        #pragma unroll
        for (int seg = 0; seg < 4; ++seg)
            a[mi][seg] = *(const v8s*)(wbuf + (size_t)m*128 + seg*32 + lr*8);
    }

    for (int nt = 0; nt < 8; ++nt) {
        const uint8_t* bp = (const uint8_t*)act + (size_t)(p0 + nt*16 + ln)*128 + lr*8;
        // B fragments: n = ln, k = seg*32 + lr*8 + j ; seg 0..1 unsigned (yq), 2..3 signed (xq)
        v8s bf[4];
        #pragma unroll
        for (int seg = 0; seg < 4; ++seg) {
            uint2 d = *(const uint2*)(bp + seg*32);
            v8s t;
            #pragma unroll
            for (int e = 0; e < 4; ++e) {
                int v0, v1;
                if (seg < 2) { v0 = (int)((d.x >> (8*e)) & 255u); v1 = (int)((d.y >> (8*e)) & 255u); }
                else         { v0 = (int)(int8_t)(d.x >> (8*e)); v1 = (int)(int8_t)(d.y >> (8*e)); }
                t[e]     = i2bf(v0);
                t[4 + e] = i2bf(v1);
            }
            bf[seg] = t;
        }
        int px = hw0 + nt*16 + ln;
        #pragma unroll
        for (int mi = 0; mi < 2; ++mi) {
            v4f acc2 = {0.f, 0.f, 0.f, 0.f};
            v4f accs = {0.f, 0.f, 0.f, 0.f};
            acc2 = __builtin_amdgcn_mfma_f32_16x16x32_bf16(a[mi][0], bf[0], acc2, 0, 0, 0);
            acc2 = __builtin_amdgcn_mfma_f32_16x16x32_bf16(a[mi][1], bf[1], acc2, 0, 0, 0);
            accs = __builtin_amdgcn_mfma_f32_16x16x32_bf16(a[mi][2], bf[2], accs, 0, 0, 0);
            accs = __builtin_amdgcn_mfma_f32_16x16x32_bf16(a[mi][3], bf[3], accs, 0, 0, 0);
            size_t obase = ((size_t)nimg*COUT + (size_t)(wave*2 + mi)*16 + lr*4) * HWI + px;
            #pragma unroll
            for (int r = 0; r < 4; ++r) {
                float v = S2 * acc2[r] + Ssc * accs[r];
                float t = rintf(v * inv_sadd);
                t = fminf(fmaxf(t, -128.0f), 127.0f);
                out[obase + (size_t)r*HWI] = t * sadd;   // FP32 store
            }
        }
    }
}

// ---------------------------------------------------------------------------
extern "C" void kernel_launch(void* const* d_in, const int* in_sizes, int n_in,
                              void* d_out, int out_size, void* d_ws, size_t ws_size,
                              hipStream_t stream) {
    const float* x     = (const float*)d_in[0];
    const float* w1    = (const float*)d_in[1];
    const float* w2    = (const float*)d_in[2];
    const float* wsc   = (const float*)d_in[3];
    const float* sin   = (const float*)d_in[4];
    const float* srelu = (const float*)d_in[5];
    const float* sadd  = (const float*)d_in[6];
    const float* sw1   = (const float*)d_in[7];
    const float* sw2   = (const float*)d_in[8];
    const float* swsc  = (const float*)d_in[9];

    int8_t*   actb = (int8_t*)d_ws;                        // NP*128 = 12.85 MB
    uint16_t* wbuf = (uint16_t*)(actb + (size_t)NP * 128); // 32 KB (bf16)

    wprep_kernel<<<1, 256, 0, stream>>>(w2, wsc, sw2, swsc, wbuf);
    dwq_kernel<<<NIMG * 56, 256, 0, stream>>>(x, w1, sin, srelu, sw1, actb);
    gemm_kernel<<<NP / 128, 256, 0, stream>>>(actb, wbuf,
                                              sin, srelu, sadd, sw2, swsc,
                                              (float*)d_out);
}

// Round 8
// 135.161 us; speedup vs baseline: 1.0391x; 1.0391x over previous
//
#include <hip/hip_runtime.h>
#include <hip/hip_bf16.h>
#include <stdint.h>

#define NIMG 8
#define CIN  64
#define HWI  12544      // 112*112
#define NP   100352     // 8*12544
#define COUT 128

typedef short v8s __attribute__((ext_vector_type(8)));   // 8 bf16 (4 VGPRs)
typedef float v4f __attribute__((ext_vector_type(4)));   // 4 fp32 acc

// fake-quant to int grid: round(x*inv) clamped to [lo,hi]
static __device__ __forceinline__ int q8(float x, float inv, float lo, float hi) {
    float t = rintf(x * inv);
    t = fminf(fmaxf(t, lo), hi);
    return (int)t;
}

// funnel shift: bytes of ({hi,lo} >> sh) — compiler emits v_alignbit_b32
static __device__ __forceinline__ uint32_t funnel(uint32_t hi, uint32_t lo, int sh) {
    return (uint32_t)(((((uint64_t)hi) << 32) | (uint64_t)lo) >> sh);
}

// manual signed-byte dot4
static __device__ __forceinline__ int dot4(uint32_t a, uint32_t b, int c) {
    int acc = c;
    #pragma unroll
    for (int i = 0; i < 4; ++i)
        acc += (int)(int8_t)(a >> (8*i)) * (int)(int8_t)(b >> (8*i));
    return acc;
}

// exact int -> bf16 bits (|v| <= 256 fits in 8 significand bits)
static __device__ __forceinline__ uint16_t i2bf(int v) {
    union { float f; uint32_t u; } c; c.f = (float)v;
    return (uint16_t)(c.u >> 16);
}

// ---------------------------------------------------------------------------
// K0: quantize 1x1 weights into bf16 matrix [128 co][128 k]
//     k<64: w2q ; k>=64: wscq.  8 blocks, coalesced float4 loads.
// ---------------------------------------------------------------------------
__global__ void __launch_bounds__(256) wprep_kernel(
    const float* __restrict__ w2, const float* __restrict__ wsc,
    const float* __restrict__ sw2p, const float* __restrict__ swscp,
    uint16_t* __restrict__ wbuf)
{
    int t = blockIdx.x * 256 + threadIdx.x;   // 2048 threads, 4 weights each
    int f = t * 4;                            // flat index into 8192-elem tensors
    int co = f >> 6, k = f & 63;
    float inv2 = 1.0f / sw2p[0];
    float invs = 1.0f / swscp[0];
    float4 a = *(const float4*)(w2 + f);
    float4 b = *(const float4*)(wsc + f);
    float av[4] = {a.x, a.y, a.z, a.w};
    float bv[4] = {b.x, b.y, b.z, b.w};
    uint16_t* d2 = wbuf + co*128 + k;
    uint16_t* ds = wbuf + co*128 + 64 + k;
    ushort2 p2a = make_ushort2(i2bf(q8(av[0], inv2, -128.f, 127.f)),
                               i2bf(q8(av[1], inv2, -128.f, 127.f)));
    ushort2 p2b = make_ushort2(i2bf(q8(av[2], inv2, -128.f, 127.f)),
                               i2bf(q8(av[3], inv2, -128.f, 127.f)));
    ushort2 psa = make_ushort2(i2bf(q8(bv[0], invs, -128.f, 127.f)),
                               i2bf(q8(bv[1], invs, -128.f, 127.f)));
    ushort2 psb = make_ushort2(i2bf(q8(bv[2], invs, -128.f, 127.f)),
                               i2bf(q8(bv[3], invs, -128.f, 127.f)));
    *(ushort2*)(d2)     = p2a;  *(ushort2*)(d2 + 2) = p2b;
    *(ushort2*)(ds)     = psa;  *(ushort2*)(ds + 2) = psb;
}

// ---------------------------------------------------------------------------
// K1: quantize x -> xq int8 (LDS), depthwise 3x3 int, relu-quant,
//     write act (bf16) [px][128]: ch 0..63 = yq, ch 64..127 = xq  (exact ints)
//     Block = (n, 2 output rows). 4 waves: (row, half-row) each.
//     LDS tile: [c][4 rows][116 cols], c-stride 468B (117 dwords, odd -> <=2-way)
// ---------------------------------------------------------------------------
__global__ void __launch_bounds__(256) dwq_kernel(
    const float* __restrict__ x, const float* __restrict__ w1,
    const float* __restrict__ sinp, const float* __restrict__ srelup,
    const float* __restrict__ sw1p,
    uint16_t* __restrict__ act)
{
    __shared__ int8_t tile[64 * 468];
    int bid = blockIdx.x;
    int n = bid / 56, ht = bid - n*56, hb = ht*2;
    int tid = threadIdx.x;
    float sin_f = sinp[0];
    float inv_sin = 1.0f / sin_f;

    for (int i = 0; i < 28; ++i) {
        int id = tid + i*256;
        int c = id / 112; int rem = id - c*112;
        int r = rem / 28; int seg = rem - r*28;
        int grow = hb + r - 1;
        float4 v = make_float4(0.f, 0.f, 0.f, 0.f);
        if ((unsigned)grow < 112u)
            v = *(const float4*)(x + ((size_t)(n*64 + c) * HWI + grow*112 + seg*4));
        float vv[4] = {v.x, v.y, v.z, v.w};
        uint32_t pk = 0;
        #pragma unroll
        for (int e = 0; e < 4; ++e) {
            int q = q8(vv[e], inv_sin, -128.0f, 127.0f);
            pk |= (uint32_t)(q & 255) << (8*e);
        }
        *(uint32_t*)&tile[c*468 + r*116 + seg*4] = pk;
    }
    {
        int c = tid >> 2, r = tid & 3;
        *(uint32_t*)&tile[c*468 + r*116 + 112] = 0;
    }
    __syncthreads();

    int wave = tid >> 6, lane = tid & 63;
    int rsel = wave >> 1;
    int row  = hb + rsel;
    int half = wave & 1;
    int c = lane;

    float isw1 = 1.0f / sw1p[0];
    uint32_t wp[3];
    #pragma unroll
    for (int ky = 0; ky < 3; ++ky) {
        uint32_t pk = 0;
        #pragma unroll
        for (int kx = 0; kx < 3; ++kx) {
            int q = q8(w1[c*9 + ky*3 + kx], isw1, -128.0f, 127.0f);
            pk |= (uint32_t)(q & 255) << (8*kx);
        }
        wp[ky] = pk;
    }
    float r1 = (sin_f * sw1p[0]) / srelup[0];

    int base[3];
    #pragma unroll
    for (int r2 = 0; r2 < 3; ++r2) base[r2] = c*468 + (rsel + r2)*116;
    int w0b = 56*half;

    uint32_t Ar[3], Br[3], Cr[3];
    #pragma unroll
    for (int r2 = 0; r2 < 3; ++r2) {
        Ar[r2] = half ? *(uint32_t*)&tile[base[r2] + w0b - 4] : 0u;
        Br[r2] = *(uint32_t*)&tile[base[r2] + w0b];
        Cr[r2] = *(uint32_t*)&tile[base[r2] + w0b + 4];
    }
    size_t pbase = (size_t)n*HWI + (size_t)row*112 + w0b;

    for (int q = 0; q < 14; ++q) {
        int acc0 = 0, acc1 = 0, acc2 = 0, acc3 = 0;
        #pragma unroll
        for (int r2 = 0; r2 < 3; ++r2) {
            uint32_t d0 = funnel(Br[r2], Ar[r2], 24);
            uint32_t d1 = Br[r2];
            uint32_t d2 = funnel(Cr[r2], Br[r2], 8);
            uint32_t d3 = funnel(Cr[r2], Br[r2], 16);
            acc0 = dot4(d0, wp[r2], acc0);
            acc1 = dot4(d1, wp[r2], acc1);
            acc2 = dot4(d2, wp[r2], acc2);
            acc3 = dot4(d3, wp[r2], acc3);
        }
        int accs[4] = {acc0, acc1, acc2, acc3};
        uint32_t xdw = Br[1];
        uint16_t* ap = act + (pbase + (size_t)q*4)*128 + c;
        #pragma unroll
        for (int j = 0; j < 4; ++j) {
            float t = rintf((float)accs[j] * r1);
            t = fminf(fmaxf(t, 0.0f), 255.0f);
            int xv = (int)(int8_t)((xdw >> (8*j)) & 255);
            ap[(size_t)j*128]      = i2bf((int)t);   // yq bf16
            ap[(size_t)j*128 + 64] = i2bf(xv);       // xq bf16
        }
        #pragma unroll
        for (int r2 = 0; r2 < 3; ++r2) { Ar[r2] = Br[r2]; Br[r2] = Cr[r2]; }
        if (q < 13) {
            #pragma unroll
            for (int r2 = 0; r2 < 3; ++r2)
                Cr[r2] = *(uint32_t*)&tile[base[r2] + w0b + q*4 + 8];
        }
    }
}

// ---------------------------------------------------------------------------
// K2: GEMM via mfma_f32_16x16x32_bf16 (exact small ints in bf16).
//     M=128 (co), K=64(yq)+64(xq) in 4 segs of 32, N=128 px/block.
//     B fragments: DIRECT v8s loads from bf16 act (no unpack).
//     Epilogue: v = S2*acc2 + Ssc*accsc ; fake_quant(s_add) ; fp32 store.
// ---------------------------------------------------------------------------
__global__ void __launch_bounds__(256) gemm_kernel(
    const uint16_t* __restrict__ act, const uint16_t* __restrict__ wbuf,
    const float* __restrict__ sinp, const float* __restrict__ srelup,
    const float* __restrict__ saddp, const float* __restrict__ sw2p,
    const float* __restrict__ swscp,
    float* __restrict__ out)
{
    int bid = blockIdx.x;                     // 784 blocks of 128 pixels
    int tid = threadIdx.x;
    int wave = tid >> 6, lane = tid & 63;
    int lr = lane >> 4, ln = lane & 15;
    int p0 = bid * 128;
    int nimg = bid / 98;                      // 12544/128 = 98 -> no n straddle
    int hw0 = (bid - nimg*98) * 128;

    float S2  = sw2p[0] * srelup[0];
    float Ssc = swscp[0] * sinp[0];
    float sadd = saddp[0];
    float inv_sadd = 1.0f / sadd;

    // A fragments: a[mi][seg], m = (wave*2+mi)*16 + ln, k = seg*32 + lr*8 + j
    v8s a[2][4];
    #pragma unroll
    for (int mi = 0; mi < 2; ++mi) {
        int m = (wave*2 + mi)*16 + ln;
        #pragma unroll
        for (int seg = 0; seg < 4; ++seg)
            a[mi][seg] = *(const v8s*)(wbuf + (size_t)m*128 + seg*32 + lr*8);
    }

    for (int nt = 0; nt < 8; ++nt) {
        const uint16_t* bp = act + (size_t)(p0 + nt*16 + ln)*128 + lr*8;
        // B fragments: n = ln, k = seg*32 + lr*8 + j — direct 16B loads
        v8s bf[4];
        #pragma unroll
        for (int seg = 0; seg < 4; ++seg)
            bf[seg] = *(const v8s*)(bp + seg*32);
        int px = hw0 + nt*16 + ln;
        #pragma unroll
        for (int mi = 0; mi < 2; ++mi) {
            v4f acc2 = {0.f, 0.f, 0.f, 0.f};
            v4f accs = {0.f, 0.f, 0.f, 0.f};
            acc2 = __builtin_amdgcn_mfma_f32_16x16x32_bf16(a[mi][0], bf[0], acc2, 0, 0, 0);
            acc2 = __builtin_amdgcn_mfma_f32_16x16x32_bf16(a[mi][1], bf[1], acc2, 0, 0, 0);
            accs = __builtin_amdgcn_mfma_f32_16x16x32_bf16(a[mi][2], bf[2], accs, 0, 0, 0);
            accs = __builtin_amdgcn_mfma_f32_16x16x32_bf16(a[mi][3], bf[3], accs, 0, 0, 0);
            size_t obase = ((size_t)nimg*COUT + (size_t)(wave*2 + mi)*16 + lr*4) * HWI + px;
            #pragma unroll
            for (int r = 0; r < 4; ++r) {
                float v = S2 * acc2[r] + Ssc * accs[r];
                float t = rintf(v * inv_sadd);
                t = fminf(fmaxf(t, -128.0f), 127.0f);
                out[obase + (size_t)r*HWI] = t * sadd;   // FP32 store
            }
        }
    }
}

// ---------------------------------------------------------------------------
extern "C" void kernel_launch(void* const* d_in, const int* in_sizes, int n_in,
                              void* d_out, int out_size, void* d_ws, size_t ws_size,
                              hipStream_t stream) {
    const float* x     = (const float*)d_in[0];
    const float* w1    = (const float*)d_in[1];
    const float* w2    = (const float*)d_in[2];
    const float* wsc   = (const float*)d_in[3];
    const float* sin   = (const float*)d_in[4];
    const float* srelu = (const float*)d_in[5];
    const float* sadd  = (const float*)d_in[6];
    const float* sw1   = (const float*)d_in[7];
    const float* sw2   = (const float*)d_in[8];
    const float* swsc  = (const float*)d_in[9];

    uint16_t* actb = (uint16_t*)d_ws;                       // NP*128*2 = 25.7 MB
    uint16_t* wbuf = actb + (size_t)NP * 128;               // 32 KB (bf16)

    wprep_kernel<<<8, 256, 0, stream>>>(w2, wsc, sw2, swsc, wbuf);
    dwq_kernel<<<NIMG * 56, 256, 0, stream>>>(x, w1, sin, srelu, sw1, actb);
    gemm_kernel<<<NP / 128, 256, 0, stream>>>(actb, wbuf,
                                              sin, srelu, sadd, sw2, swsc,
                                              (float*)d_out);
}

// Round 9
// 120.913 us; speedup vs baseline: 1.1615x; 1.1178x over previous
//
#include <hip/hip_runtime.h>
#include <hip/hip_bf16.h>
#include <stdint.h>

#define NIMG 8
#define CIN  64
#define HWI  12544      // 112*112
#define NP   100352     // 8*12544
#define COUT 128

typedef short v8s __attribute__((ext_vector_type(8)));   // 8 bf16 (4 VGPRs)
typedef float v4f __attribute__((ext_vector_type(4)));   // 4 fp32 acc

// fake-quant to int grid: round(x*inv) clamped to [lo,hi]
static __device__ __forceinline__ int q8(float x, float inv, float lo, float hi) {
    float t = rintf(x * inv);
    t = fminf(fmaxf(t, lo), hi);
    return (int)t;
}

// funnel shift: bytes of ({hi,lo} >> sh) — compiler emits v_alignbit_b32
static __device__ __forceinline__ uint32_t funnel(uint32_t hi, uint32_t lo, int sh) {
    return (uint32_t)(((((uint64_t)hi) << 32) | (uint64_t)lo) >> sh);
}

// manual signed-byte dot4
static __device__ __forceinline__ int dot4(uint32_t a, uint32_t b, int c) {
    int acc = c;
    #pragma unroll
    for (int i = 0; i < 4; ++i)
        acc += (int)(int8_t)(a >> (8*i)) * (int)(int8_t)(b >> (8*i));
    return acc;
}

// exact int -> bf16 bits (|v| <= 256 fits in 8 significand bits)
static __device__ __forceinline__ uint16_t i2bf(int v) {
    union { float f; uint32_t u; } c; c.f = (float)v;
    return (uint16_t)(c.u >> 16);
}

// ---------------------------------------------------------------------------
// K0: quantize 1x1 weights into bf16 matrix [128 co][128 k]
//     k<64: w2q ; k>=64: wscq.  8 blocks, coalesced float4 loads.
// ---------------------------------------------------------------------------
__global__ void __launch_bounds__(256) wprep_kernel(
    const float* __restrict__ w2, const float* __restrict__ wsc,
    const float* __restrict__ sw2p, const float* __restrict__ swscp,
    uint16_t* __restrict__ wbuf)
{
    int t = blockIdx.x * 256 + threadIdx.x;   // 2048 threads, 4 weights each
    int f = t * 4;
    int co = f >> 6, k = f & 63;
    float inv2 = 1.0f / sw2p[0];
    float invs = 1.0f / swscp[0];
    float4 a = *(const float4*)(w2 + f);
    float4 b = *(const float4*)(wsc + f);
    float av[4] = {a.x, a.y, a.z, a.w};
    float bv[4] = {b.x, b.y, b.z, b.w};
    uint16_t* d2 = wbuf + co*128 + k;
    uint16_t* ds = wbuf + co*128 + 64 + k;
    *(ushort2*)(d2)     = make_ushort2(i2bf(q8(av[0], inv2, -128.f, 127.f)),
                                       i2bf(q8(av[1], inv2, -128.f, 127.f)));
    *(ushort2*)(d2 + 2) = make_ushort2(i2bf(q8(av[2], inv2, -128.f, 127.f)),
                                       i2bf(q8(av[3], inv2, -128.f, 127.f)));
    *(ushort2*)(ds)     = make_ushort2(i2bf(q8(bv[0], invs, -128.f, 127.f)),
                                       i2bf(q8(bv[1], invs, -128.f, 127.f)));
    *(ushort2*)(ds + 2) = make_ushort2(i2bf(q8(bv[2], invs, -128.f, 127.f)),
                                       i2bf(q8(bv[3], invs, -128.f, 127.f)));
}

// ---------------------------------------------------------------------------
// K1 (fused): x -> quant -> depthwise -> relu-quant -> (LDS) -> MFMA GEMM
//             (conv2 + shortcut) -> requant -> fp32 out.  No act round-trip.
//     Block = (n, 2 output rows) = 448 blocks x 256 threads.
//     tile: int8 [c][4 rows][116+pad], c-stride 468 B (odd dwords).
//     Bl:   int8 [224 px][132 B]; k 0..63 = yq (uint8), 64..127 = xq (int8).
//     LDS total = 29952 + 29568 = 59520 B -> 2 blocks/CU.
// ---------------------------------------------------------------------------
__global__ void __launch_bounds__(256) fused_kernel(
    const float* __restrict__ x, const float* __restrict__ w1,
    const uint16_t* __restrict__ wbuf,
    const float* __restrict__ sinp, const float* __restrict__ srelup,
    const float* __restrict__ saddp, const float* __restrict__ sw1p,
    const float* __restrict__ sw2p, const float* __restrict__ swscp,
    float* __restrict__ out)
{
    __shared__ int8_t tile[64 * 468];   // 29952 B
    __shared__ int8_t Bl[224 * 132];    // 29568 B

    int bid = blockIdx.x;
    int n = bid / 56, ht = bid - n*56, hb = ht*2;
    int tid = threadIdx.x;
    int wave = tid >> 6, lane = tid & 63;
    float sin_f = sinp[0];
    float inv_sin = 1.0f / sin_f;

    // ---- phase 1: stage + quantize 4 halo rows x 64 ch x 112 into tile ----
    for (int i = 0; i < 28; ++i) {
        int id = tid + i*256;
        int c = id / 112; int rem = id - c*112;
        int r = rem / 28; int seg = rem - r*28;
        int grow = hb + r - 1;
        float4 v = make_float4(0.f, 0.f, 0.f, 0.f);
        if ((unsigned)grow < 112u)
            v = *(const float4*)(x + ((size_t)(n*64 + c) * HWI + grow*112 + seg*4));
        float vv[4] = {v.x, v.y, v.z, v.w};
        uint32_t pk = 0;
        #pragma unroll
        for (int e = 0; e < 4; ++e) {
            int q = q8(vv[e], inv_sin, -128.0f, 127.0f);
            pk |= (uint32_t)(q & 255) << (8*e);
        }
        *(uint32_t*)&tile[c*468 + r*116 + seg*4] = pk;
    }
    {
        int c = tid >> 2, r = tid & 3;
        *(uint32_t*)&tile[c*468 + r*116 + 112] = 0;
    }
    __syncthreads();

    // ---- phase 2: depthwise 3x3 + relu-quant; write yq/xq bytes into Bl ----
    {
        int rsel = wave >> 1;             // which of the 2 output rows
        int half = wave & 1;              // which half of the 112-wide row
        int c = lane;

        float isw1 = 1.0f / sw1p[0];
        uint32_t wp[3];
        #pragma unroll
        for (int ky = 0; ky < 3; ++ky) {
            uint32_t pk = 0;
            #pragma unroll
            for (int kx = 0; kx < 3; ++kx) {
                int q = q8(w1[c*9 + ky*3 + kx], isw1, -128.0f, 127.0f);
                pk |= (uint32_t)(q & 255) << (8*kx);
            }
            wp[ky] = pk;
        }
        float r1 = (sin_f * sw1p[0]) / srelup[0];

        int base[3];
        #pragma unroll
        for (int r2 = 0; r2 < 3; ++r2) base[r2] = c*468 + (rsel + r2)*116;
        int w0b = 56*half;

        uint32_t Ar[3], Br[3], Cr[3];
        #pragma unroll
        for (int r2 = 0; r2 < 3; ++r2) {
            Ar[r2] = half ? *(uint32_t*)&tile[base[r2] + w0b - 4] : 0u;
            Br[r2] = *(uint32_t*)&tile[base[r2] + w0b];
            Cr[r2] = *(uint32_t*)&tile[base[r2] + w0b + 4];
        }

        for (int q = 0; q < 14; ++q) {
            int acc0 = 0, acc1 = 0, acc2 = 0, acc3 = 0;
            #pragma unroll
            for (int r2 = 0; r2 < 3; ++r2) {
                uint32_t d0 = funnel(Br[r2], Ar[r2], 24);
                uint32_t d1 = Br[r2];
                uint32_t d2 = funnel(Cr[r2], Br[r2], 8);
                uint32_t d3 = funnel(Cr[r2], Br[r2], 16);
                acc0 = dot4(d0, wp[r2], acc0);
                acc1 = dot4(d1, wp[r2], acc1);
                acc2 = dot4(d2, wp[r2], acc2);
                acc3 = dot4(d3, wp[r2], acc3);
            }
            int accs[4] = {acc0, acc1, acc2, acc3};
            uint32_t xdw = Br[1];
            int pxb = rsel*112 + w0b + q*4;
            #pragma unroll
            for (int j = 0; j < 4; ++j) {
                float t = rintf((float)accs[j] * r1);
                t = fminf(fmaxf(t, 0.0f), 255.0f);
                Bl[(pxb + j)*132 + c]      = (int8_t)(int)t;                 // yq
                Bl[(pxb + j)*132 + 64 + c] = (int8_t)((xdw >> (8*j)) & 255); // xq
            }
            #pragma unroll
            for (int r2 = 0; r2 < 3; ++r2) { Ar[r2] = Br[r2]; Br[r2] = Cr[r2]; }
            if (q < 13) {
                #pragma unroll
                for (int r2 = 0; r2 < 3; ++r2)
                    Cr[r2] = *(uint32_t*)&tile[base[r2] + w0b + q*4 + 8];
            }
        }
    }
    __syncthreads();

    // ---- phase 3: GEMM (mfma_f32_16x16x32_bf16) + requant epilogue ----
    {
        int lr = lane >> 4, ln = lane & 15;

        float S2  = sw2p[0] * srelup[0];
        float Ssc = swscp[0] * sinp[0];
        float sadd = saddp[0];
        float inv_sadd = 1.0f / sadd;

        // A fragments: m = (wave*2+mi)*16 + ln, k = seg*32 + lr*8 + j
        v8s a[2][4];
        #pragma unroll
        for (int mi = 0; mi < 2; ++mi) {
            int m = (wave*2 + mi)*16 + ln;
            #pragma unroll
            for (int seg = 0; seg < 4; ++seg)
                a[mi][seg] = *(const v8s*)(wbuf + (size_t)m*128 + seg*32 + lr*8);
        }

        size_t orow = (size_t)n*COUT*HWI + (size_t)hb*112;

        for (int nt = 0; nt < 14; ++nt) {
            int boff = (nt*16 + ln)*132 + lr*8;
            v8s bf[4];
            #pragma unroll
            for (int seg = 0; seg < 4; ++seg) {
                uint32_t d0 = *(const uint32_t*)&Bl[boff + seg*32];
                uint32_t d1 = *(const uint32_t*)&Bl[boff + seg*32 + 4];
                v8s t;
                if (seg < 2) {
                    #pragma unroll
                    for (int e = 0; e < 4; ++e) {
                        t[e]     = (short)i2bf((int)((d0 >> (8*e)) & 255u));
                        t[4 + e] = (short)i2bf((int)((d1 >> (8*e)) & 255u));
                    }
                } else {
                    #pragma unroll
                    for (int e = 0; e < 4; ++e) {
                        t[e]     = (short)i2bf((int)(int8_t)(d0 >> (8*e)));
                        t[4 + e] = (short)i2bf((int)(int8_t)(d1 >> (8*e)));
                    }
                }
                bf[seg] = t;
            }
            #pragma unroll
            for (int mi = 0; mi < 2; ++mi) {
                v4f acc2 = {0.f, 0.f, 0.f, 0.f};
                v4f accs = {0.f, 0.f, 0.f, 0.f};
                acc2 = __builtin_amdgcn_mfma_f32_16x16x32_bf16(a[mi][0], bf[0], acc2, 0, 0, 0);
                acc2 = __builtin_amdgcn_mfma_f32_16x16x32_bf16(a[mi][1], bf[1], acc2, 0, 0, 0);
                accs = __builtin_amdgcn_mfma_f32_16x16x32_bf16(a[mi][2], bf[2], accs, 0, 0, 0);
                accs = __builtin_amdgcn_mfma_f32_16x16x32_bf16(a[mi][3], bf[3], accs, 0, 0, 0);
                size_t obase = orow + (size_t)((wave*2 + mi)*16 + lr*4)*HWI + nt*16 + ln;
                #pragma unroll
                for (int r = 0; r < 4; ++r) {
                    float v = S2 * acc2[r] + Ssc * accs[r];
                    float t = rintf(v * inv_sadd);
                    t = fminf(fmaxf(t, -128.0f), 127.0f);
                    out[obase + (size_t)r*HWI] = t * sadd;
                }
            }
        }
    }
}

// ---------------------------------------------------------------------------
extern "C" void kernel_launch(void* const* d_in, const int* in_sizes, int n_in,
                              void* d_out, int out_size, void* d_ws, size_t ws_size,
                              hipStream_t stream) {
    const float* x     = (const float*)d_in[0];
    const float* w1    = (const float*)d_in[1];
    const float* w2    = (const float*)d_in[2];
    const float* wsc   = (const float*)d_in[3];
    const float* sin   = (const float*)d_in[4];
    const float* srelu = (const float*)d_in[5];
    const float* sadd  = (const float*)d_in[6];
    const float* sw1   = (const float*)d_in[7];
    const float* sw2   = (const float*)d_in[8];
    const float* swsc  = (const float*)d_in[9];

    uint16_t* wbuf = (uint16_t*)d_ws;   // 32 KB (bf16 weight matrix)

    wprep_kernel<<<8, 256, 0, stream>>>(w2, wsc, sw2, swsc, wbuf);
    fused_kernel<<<NIMG * 56, 256, 0, stream>>>(x, w1, wbuf,
                                                sin, srelu, sadd, sw1, sw2, swsc,
                                                (float*)d_out);
}